// Round 1
// baseline (210.321 us; speedup 1.0000x reference)
//
#include <hip/hip_runtime.h>

#define BB 32
#define NN 1024
#define FF 7
#define HID 256
#define MLPH 64
#define OUTN 8
#define CATN (MLPH + HID + 8)   // 328

__device__ __forceinline__ float wave_sum(float v) {
#pragma unroll
    for (int m = 32; m >= 1; m >>= 1) v += __shfl_xor(v, m, 64);
    return v;
}
__device__ __forceinline__ float wave_max(float v) {
#pragma unroll
    for (int m = 32; m >= 1; m >>= 1) v = fmaxf(v, __shfl_xor(v, m, 64));
    return v;
}

// K1: all producer work with no internal dependencies, one launch.
//   blocks [0,256):   A-pass per (b,jg): degree row + pairwise d2 max.
//                     Self-extracts pts from x (stride-7 LDS read: gcd(7,32)=1,
//                     bank-conflict-free) so it does not depend on the repack.
//   blocks [256,288): repack x -> pts SoA (for K2's cheap 8KB staging) + speed
//                     sum + done[b]=0 reset for K2's fan-in counter.
//   blocks [288,296): weight collapse E = (Wp_gcn@Wfc)@W2, cE.
//   blocks [296,424): MLP-L1 GEMV, 2 blocks per h row (16 batches per block).
union S1 {
    struct { float xb[NN * FF]; float l0[NN], l1[NN], s2[NN], s3[NN]; float wred[16]; } a; // 44.1 KB
    struct { float xb[NN * FF]; float wred[16]; } p;
    struct { float l0[HID], l1[HID], r2[HID]; float wred[16]; } c;
    struct { float wb[NN * FF]; } m;
};

__global__ __launch_bounds__(1024, 4) void k1(const float* __restrict__ x,
                                              const float* __restrict__ Wm0,
                                              const float* __restrict__ W2,
                                              const float* __restrict__ b2,
                                              const float* __restrict__ Wfc,
                                              const float* __restrict__ bfc,
                                              const float* __restrict__ Wp,
                                              float* __restrict__ pts0,
                                              float* __restrict__ pts1,
                                              float* __restrict__ spd,
                                              float* __restrict__ mlp_p,
                                              float* __restrict__ E,
                                              float* __restrict__ cE,
                                              float* __restrict__ deg,
                                              float* __restrict__ bmaxp,
                                              int* __restrict__ done) {
    __shared__ __align__(16) S1 sm;
    int blk = blockIdx.x, tid = threadIdx.x, lane = tid & 63, w = tid >> 6;
    if (blk < 256) {
        // ---- A-pass ----
        int b = blk >> 3, jg = blk & 7;
        const float4* xr = (const float4*)(x + b * (NN * FF));
        float4* s4 = (float4*)sm.a.xb;
        for (int i = tid; i < 1792; i += 1024) s4[i] = xr[i];
        __syncthreads();
        sm.a.l0[tid] = sm.a.xb[tid * FF + 1];
        sm.a.l1[tid] = sm.a.xb[tid * FF + 2];
        __syncthreads();
        int jA = jg * 128 + lane, jB = jA + 64;
        float pj0a = sm.a.l0[jA], pj1a = sm.a.l1[jA];
        float pj0b = sm.a.l0[jB], pj1b = sm.a.l1[jB];
        const float4* v0p = (const float4*)&sm.a.l0[w * 64];
        const float4* v1p = (const float4*)&sm.a.l1[w * 64];
        unsigned dA = 0u, dB = 0u;
        float mx = 0.f;
#pragma unroll 4
        for (int g = 0; g < 16; ++g) {
            float4 v0 = v0p[g], v1 = v1p[g];
            float dx, dy, d2a, d2b;
            dx = pj0a - v0.x; dy = pj1a - v1.x; d2a = fmaf(dy, dy, dx * dx);
            dx = pj0b - v0.x; dy = pj1b - v1.x; d2b = fmaf(dy, dy, dx * dx);
            dA += (d2a <= 0.09f); dB += (d2b <= 0.09f);
            mx = fmaxf(mx, fmaxf(d2a, d2b));
            dx = pj0a - v0.y; dy = pj1a - v1.y; d2a = fmaf(dy, dy, dx * dx);
            dx = pj0b - v0.y; dy = pj1b - v1.y; d2b = fmaf(dy, dy, dx * dx);
            dA += (d2a <= 0.09f); dB += (d2b <= 0.09f);
            mx = fmaxf(mx, fmaxf(d2a, d2b));
            dx = pj0a - v0.z; dy = pj1a - v1.z; d2a = fmaf(dy, dy, dx * dx);
            dx = pj0b - v0.z; dy = pj1b - v1.z; d2b = fmaf(dy, dy, dx * dx);
            dA += (d2a <= 0.09f); dB += (d2b <= 0.09f);
            mx = fmaxf(mx, fmaxf(d2a, d2b));
            dx = pj0a - v0.w; dy = pj1a - v1.w; d2a = fmaf(dy, dy, dx * dx);
            dx = pj0b - v0.w; dy = pj1b - v1.w; d2b = fmaf(dy, dy, dx * dx);
            dA += (d2a <= 0.09f); dB += (d2b <= 0.09f);
            mx = fmaxf(mx, fmaxf(d2a, d2b));
        }
        sm.a.s2[tid] = (float)dA;
        sm.a.s3[tid] = (float)dB;
        mx = wave_max(mx);
        if (lane == 0) sm.a.wred[w] = mx;
        __syncthreads();
        if (tid < 64) {
            float s = 0.f;
#pragma unroll
            for (int kk = 0; kk < 16; ++kk) s += sm.a.s2[kk * 64 + tid];
            deg[b * NN + jg * 128 + tid] = s;
        } else if (tid < 128) {
            int t = tid - 64;
            float s = 0.f;
#pragma unroll
            for (int kk = 0; kk < 16; ++kk) s += sm.a.s3[kk * 64 + t];
            deg[b * NN + jg * 128 + 64 + t] = s;
        }
        if (tid == 0) {
            float m = sm.a.wred[0];
#pragma unroll
            for (int i = 1; i < 16; ++i) m = fmaxf(m, sm.a.wred[i]);
            bmaxp[b * 8 + jg] = m;
        }
    } else if (blk < 288) {
        // ---- repack + speed + fan-in counter reset ----
        int b = blk - 256;
        const float4* xr = (const float4*)(x + b * (NN * FF));
        float4* s4 = (float4*)sm.p.xb;
        for (int i = tid; i < 1792; i += 1024) s4[i] = xr[i];
        __syncthreads();
        pts0[b * NN + tid] = sm.p.xb[tid * FF + 1];
        pts1[b * NN + tid] = sm.p.xb[tid * FF + 2];
        float vx = sm.p.xb[tid * FF + 3], vy = sm.p.xb[tid * FF + 4];
        float sp = sqrtf(fmaf(vx, vx, vy * vy));
        sp = wave_sum(sp);
        if (lane == 0) sm.p.wred[w] = sp;
        __syncthreads();
        if (tid == 0) {
            float s = 0.f;
#pragma unroll
            for (int i = 0; i < 16; ++i) s += sm.p.wred[i];
            spd[b] = s;
            done[b] = 0;
        }
    } else if (blk < 296) {
        // ---- weight collapse ----
        int o = blk - 288;
        if (tid < HID) sm.c.l0[tid] = Wp[o * CATN + MLPH + tid];
        __syncthreads();
        if (tid < HID) {
            float a = 0.f;
#pragma unroll 8
            for (int m = 0; m < HID; ++m) a = fmaf(sm.c.l0[m], Wfc[m * HID + tid], a);
            sm.c.l1[tid] = a;
            sm.c.r2[tid] = sm.c.l0[tid] * bfc[tid];
        }
        __syncthreads();
        if (tid < HID) {
            float e = 0.f;
#pragma unroll 8
            for (int k = 0; k < HID; ++k) e = fmaf(sm.c.l1[k], W2[k * HID + tid], e);
            E[o * HID + tid] = e;
            float c = fmaf(sm.c.l1[tid], b2[tid], sm.c.r2[tid]);
            c = wave_sum(c);
            if (lane == 0) sm.c.wred[w] = c;
        }
        __syncthreads();
        if (tid == 0) cE[o] = sm.c.wred[0] + sm.c.wred[1] + sm.c.wred[2] + sm.c.wred[3];
    } else {
        // ---- MLP-L1 GEMV: 2 blocks per h, 16 batches (1 per wave) each ----
        int t = blk - 296, h = t >> 1, half = t & 1;
        const float4* wr = (const float4*)(Wm0 + h * (NN * FF));
        float4* s4 = (float4*)sm.m.wb;
        for (int i = tid; i < 1792; i += 1024) s4[i] = wr[i];
        __syncthreads();
        int b = half * 16 + w;
        const float4* xr = (const float4*)(x + b * (NN * FF));
        float4 a4 = {0.f, 0.f, 0.f, 0.f};
#pragma unroll 7
        for (int it = 0; it < 28; ++it) {
            float4 xv = xr[it * 64 + lane];
            float4 wv = s4[it * 64 + lane];
            a4.x = fmaf(wv.x, xv.x, a4.x);
            a4.y = fmaf(wv.y, xv.y, a4.y);
            a4.z = fmaf(wv.z, xv.z, a4.z);
            a4.w = fmaf(wv.w, xv.w, a4.w);
        }
        float s = (a4.x + a4.y) + (a4.z + a4.w);
        s = wave_sum(s);
        if (lane == 0) mlp_p[b * MLPH + h] = s;
    }
}

// K2: B-pass per (b,jg) with FUSED h/hsum partial (q-triples never leave LDS),
// then device-scope atomic fan-in: the 8th-arriving block of each batch runs
// the tiny epilogue (old kF minus the heavy hsum). Deadlock-free under any
// dispatch order (no spinning), deterministic (same math whoever wins).
union S2 {
    struct {
        float l0[NN], l1[NN], di[NN];
        float r0a[NN], r1a[NN], r2a[NN], r0b[NN], r1b[NN], r2b[NN];
        float q0[128], q1[128], qw[128];
    } b;                                                   // 37.5 KB
    struct { float hs[HID]; float sx1[MLPH]; float sxf2[MLPH]; float sglo[8]; } f;
};

__global__ __launch_bounds__(1024, 4) void k2(const float* __restrict__ pts0,
                                              const float* __restrict__ pts1,
                                              const float* __restrict__ deg,
                                              const float* __restrict__ W1,
                                              const float* __restrict__ b1,
                                              const float* __restrict__ Wg,
                                              const float* __restrict__ bg,
                                              const float* __restrict__ Wm1,
                                              const float* __restrict__ bm1,
                                              const float* __restrict__ Wp,
                                              const float* __restrict__ bp,
                                              const float* __restrict__ bm0,
                                              const float* __restrict__ mlp_p,
                                              const float* __restrict__ bmaxp,
                                              const float* __restrict__ spd,
                                              const float* __restrict__ E,
                                              const float* __restrict__ cE,
                                              float* __restrict__ hpart,
                                              int* __restrict__ done,
                                              float* __restrict__ out) {
    __shared__ __align__(16) S2 sm;
    __shared__ int lastflag;
    int blk = blockIdx.x, tid = threadIdx.x, lane = tid & 63, w = tid >> 6;
    int b = blk >> 3, jg = blk & 7;
    sm.b.l0[tid] = pts0[b * NN + tid];
    sm.b.l1[tid] = pts1[b * NN + tid];
    sm.b.di[tid] = 1.0f / sqrtf(deg[b * NN + tid]);
    __syncthreads();
    int jA = jg * 128 + lane, jB = jA + 64;
    float pj0a = sm.b.l0[jA], pj1a = sm.b.l1[jA];
    float pj0b = sm.b.l0[jB], pj1b = sm.b.l1[jB];
    const float4* v0p = (const float4*)&sm.b.l0[w * 64];
    const float4* v1p = (const float4*)&sm.b.l1[w * 64];
    const float4* vdp = (const float4*)&sm.b.di[w * 64];
    float a0a = 0.f, a1a = 0.f, asa = 0.f;
    float a0b = 0.f, a1b = 0.f, asb = 0.f;
#pragma unroll 4
    for (int g = 0; g < 16; ++g) {
        float4 v0 = v0p[g], v1 = v1p[g], vd = vdp[g];
        float dx, dy, d2, t;
        dx = pj0a - v0.x; dy = pj1a - v1.x; d2 = fmaf(dy, dy, dx * dx);
        t = (d2 <= 0.09f) ? vd.x : 0.0f;
        a0a = fmaf(t, v0.x, a0a); a1a = fmaf(t, v1.x, a1a); asa += t;
        dx = pj0b - v0.x; dy = pj1b - v1.x; d2 = fmaf(dy, dy, dx * dx);
        t = (d2 <= 0.09f) ? vd.x : 0.0f;
        a0b = fmaf(t, v0.x, a0b); a1b = fmaf(t, v1.x, a1b); asb += t;
        dx = pj0a - v0.y; dy = pj1a - v1.y; d2 = fmaf(dy, dy, dx * dx);
        t = (d2 <= 0.09f) ? vd.y : 0.0f;
        a0a = fmaf(t, v0.y, a0a); a1a = fmaf(t, v1.y, a1a); asa += t;
        dx = pj0b - v0.y; dy = pj1b - v1.y; d2 = fmaf(dy, dy, dx * dx);
        t = (d2 <= 0.09f) ? vd.y : 0.0f;
        a0b = fmaf(t, v0.y, a0b); a1b = fmaf(t, v1.y, a1b); asb += t;
        dx = pj0a - v0.z; dy = pj1a - v1.z; d2 = fmaf(dy, dy, dx * dx);
        t = (d2 <= 0.09f) ? vd.z : 0.0f;
        a0a = fmaf(t, v0.z, a0a); a1a = fmaf(t, v1.z, a1a); asa += t;
        dx = pj0b - v0.z; dy = pj1b - v1.z; d2 = fmaf(dy, dy, dx * dx);
        t = (d2 <= 0.09f) ? vd.z : 0.0f;
        a0b = fmaf(t, v0.z, a0b); a1b = fmaf(t, v1.z, a1b); asb += t;
        dx = pj0a - v0.w; dy = pj1a - v1.w; d2 = fmaf(dy, dy, dx * dx);
        t = (d2 <= 0.09f) ? vd.w : 0.0f;
        a0a = fmaf(t, v0.w, a0a); a1a = fmaf(t, v1.w, a1a); asa += t;
        dx = pj0b - v0.w; dy = pj1b - v1.w; d2 = fmaf(dy, dy, dx * dx);
        t = (d2 <= 0.09f) ? vd.w : 0.0f;
        a0b = fmaf(t, v0.w, a0b); a1b = fmaf(t, v1.w, a1b); asb += t;
    }
    sm.b.r0a[tid] = a0a; sm.b.r1a[tid] = a1a; sm.b.r2a[tid] = asa;
    sm.b.r0b[tid] = a0b; sm.b.r1b[tid] = a1b; sm.b.r2b[tid] = asb;
    __syncthreads();
    if (tid < 128) {
        int t = tid & 63;
        const float* R0 = (tid < 64) ? sm.b.r0a : sm.b.r0b;
        const float* R1 = (tid < 64) ? sm.b.r1a : sm.b.r1b;
        const float* R2 = (tid < 64) ? sm.b.r2a : sm.b.r2b;
        int j = jg * 128 + tid;     // local index == tid for tid<128
        float s0 = 0.f, s1 = 0.f, ss = 0.f;
#pragma unroll
        for (int kk = 0; kk < 16; ++kk) {
            s0 += R0[kk * 64 + t];
            s1 += R1[kk * 64 + t];
            ss += R2[kk * 64 + t];
        }
        float dj = sm.b.di[j];
        sm.b.q0[tid] = dj * s0;
        sm.b.q1[tid] = dj * s1;
        sm.b.qw[tid] = dj * ss * (1.0f / NN);
    }
    __syncthreads();
    // ---- fused h + weighted hsum partial over this block's 128 j ----
    {
        int h = tid & 255, jq = tid >> 8;
        float w10 = W1[2 * h], w11 = W1[2 * h + 1], bb = b1[h];
        const float4* q0v = (const float4*)&sm.b.q0[jq * 32];
        const float4* q1v = (const float4*)&sm.b.q1[jq * 32];
        const float4* qwv = (const float4*)&sm.b.qw[jq * 32];
        float acc = 0.f;
#pragma unroll
        for (int g = 0; g < 8; ++g) {
            float4 qa = q0v[g], qb = q1v[g], qw4 = qwv[g];
            acc = fmaf(qw4.x, fmaxf(fmaf(qb.x, w11, fmaf(qa.x, w10, bb)), 0.f), acc);
            acc = fmaf(qw4.y, fmaxf(fmaf(qb.y, w11, fmaf(qa.y, w10, bb)), 0.f), acc);
            acc = fmaf(qw4.z, fmaxf(fmaf(qb.z, w11, fmaf(qa.z, w10, bb)), 0.f), acc);
            acc = fmaf(qw4.w, fmaxf(fmaf(qb.w, w11, fmaf(qa.w, w10, bb)), 0.f), acc);
        }
        sm.b.r0a[jq * 256 + h] = acc;   // r-arrays dead after the sync above
    }
    __syncthreads();
    if (tid < HID) {
        float s = sm.b.r0a[tid] + sm.b.r0a[256 + tid] + sm.b.r0a[512 + tid] + sm.b.r0a[768 + tid];
        hpart[(b * 8 + jg) * HID + tid] = s;
    }
    __threadfence();                    // release hpart (device scope, cross-XCD)
    __syncthreads();
    if (tid == 0) lastflag = (atomicAdd(&done[b], 1) == 7);
    __syncthreads();
    if (!lastflag) return;
    __threadfence();                    // acquire before reading peers' hpart
    // ---- epilogue (old kF minus the heavy hsum), once per batch ----
    if (tid < HID) {
        float s = 0.f;
#pragma unroll
        for (int g = 0; g < 8; ++g) s += hpart[(b * 8 + g) * HID + tid];
        sm.f.hs[tid] = s;
    } else if (tid < HID + MLPH) {
        int t2 = tid - HID;
        sm.f.sx1[t2] = fmaxf(mlp_p[b * MLPH + t2] + bm0[t2], 0.f);
    } else if (tid < HID + MLPH + 8) {
        int t2 = tid - HID - MLPH;
        float mx = 0.f;
#pragma unroll
        for (int g = 0; g < 8; ++g) mx = fmaxf(mx, bmaxp[b * 8 + g]);
        float avg  = spd[b] * (1.0f / NN);
        float dens = 1.0f / sqrtf(mx);
        sm.f.sglo[t2] = fmaxf(fmaf(Wg[t2 * 2], avg, fmaf(Wg[t2 * 2 + 1], dens, bg[t2])), 0.f);
    }
    __syncthreads();
    if (tid < MLPH) {
        float a = bm1[tid];
        const float* wv = Wm1 + tid * MLPH;
#pragma unroll
        for (int k = 0; k < MLPH; ++k) a = fmaf(wv[k], sm.f.sx1[k], a);
        sm.f.sxf2[tid] = fmaxf(a, 0.f);
    }
    __syncthreads();
    if (tid < 512) {
        int o = tid >> 6, ln = tid & 63;
        const float* Eo = E + o * HID;
        float a = Eo[ln] * sm.f.hs[ln];
        a = fmaf(Eo[ln + 64],  sm.f.hs[ln + 64],  a);
        a = fmaf(Eo[ln + 128], sm.f.hs[ln + 128], a);
        a = fmaf(Eo[ln + 192], sm.f.hs[ln + 192], a);
        a = fmaf(Wp[o * CATN + ln], sm.f.sxf2[ln], a);
        a = wave_sum(a);
        if (ln == 0) {
            const float* wg = Wp + o * CATN + MLPH + HID;
            float r = a;
#pragma unroll
            for (int g = 0; g < 8; ++g) r = fmaf(wg[g], sm.f.sglo[g], r);
            out[b * OUTN + o] = r + cE[o] + bp[o];
        }
    }
}

extern "C" void kernel_launch(void* const* d_in, const int* in_sizes, int n_in,
                              void* d_out, int out_size, void* d_ws, size_t ws_size,
                              hipStream_t stream) {
    const float* x   = (const float*)d_in[0];
    const float* W1  = (const float*)d_in[1];
    const float* b1  = (const float*)d_in[2];
    const float* W2  = (const float*)d_in[3];
    const float* b2  = (const float*)d_in[4];
    const float* Wfc = (const float*)d_in[5];
    const float* bfc = (const float*)d_in[6];
    const float* Wg  = (const float*)d_in[7];
    const float* bg  = (const float*)d_in[8];
    const float* Wm0 = (const float*)d_in[9];
    const float* bm0 = (const float*)d_in[10];
    const float* Wm1 = (const float*)d_in[11];
    const float* bm1 = (const float*)d_in[12];
    const float* Wp  = (const float*)d_in[13];
    const float* bp  = (const float*)d_in[14];
    float* out = (float*)d_out;
    float* ws  = (float*)d_ws;

    float* pts0  = ws;              // 32768
    float* pts1  = ws + 32768;      // 32768
    float* deg   = ws + 65536;      // 32768
    float* mlp_p = ws + 98304;      // 2048
    float* bmaxp = ws + 100352;     // 256
    float* spd   = ws + 100608;     // 32
    float* E     = ws + 100640;     // 2048
    float* cE    = ws + 102688;     // 8 (+pad to 102720)
    int*   done  = (int*)(ws + 102720);   // 32 ints, reset by K1 each iteration
    float* hpart = ws + 102752;     // 32*8*256 = 65536
    // every ws cell is written before it is read each iteration -> no zero-init.

    k1<<<424, 1024, 0, stream>>>(x, Wm0, W2, b2, Wfc, bfc, Wp,
                                 pts0, pts1, spd, mlp_p, E, cE, deg, bmaxp, done);
    k2<<<256, 1024, 0, stream>>>(pts0, pts1, deg, W1, b1, Wg, bg, Wm1, bm1,
                                 Wp, bp, bm0, mlp_p, bmaxp, spd, E, cE,
                                 hpart, done, out);
}

// Round 2
// 123.531 us; speedup vs baseline: 1.7026x; 1.7026x over previous
//
#include <hip/hip_runtime.h>

#define BB 32
#define NN 1024
#define FF 7
#define HID 256
#define MLPH 64
#define OUTN 8
#define CATN (MLPH + HID + 8)   // 328

__device__ __forceinline__ float wave_sum(float v) {
#pragma unroll
    for (int m = 32; m >= 1; m >>= 1) v += __shfl_xor(v, m, 64);
    return v;
}
__device__ __forceinline__ float wave_max(float v) {
#pragma unroll
    for (int m = 32; m >= 1; m >>= 1) v = fmaxf(v, __shfl_xor(v, m, 64));
    return v;
}

// K1: all producer work with no internal dependencies, one launch.
//   blocks [0,256):   A-pass per (b,jg): degree row + pairwise d2 max.
//                     Self-extracts pts from x (stride-7 LDS read: gcd(7,32)=1 ->
//                     2-way bank aliasing only, which is free).
//   blocks [256,288): repack x -> pts SoA (for K2's cheap 8KB staging) + speed
//                     sum + out[b][:]=0 (K2 accumulates into out with atomics).
//   blocks [288,296): weight collapse E = (Wp_gcn@Wfc)@W2, cE.
//   blocks [296,424): MLP-L1 GEMV, 2 blocks per h row (16 batches per block).
union S1 {
    struct { float xb[NN * FF]; float l0[NN], l1[NN], s2[NN], s3[NN]; float wred[16]; } a; // 45.1 KB
    struct { float xb[NN * FF]; float wred[16]; } p;
    struct { float l0[HID], l1[HID], r2[HID]; float wred[16]; } c;
    struct { float wb[NN * FF]; } m;
};

__global__ __launch_bounds__(1024, 4) void k1(const float* __restrict__ x,
                                              const float* __restrict__ Wm0,
                                              const float* __restrict__ W2,
                                              const float* __restrict__ b2,
                                              const float* __restrict__ Wfc,
                                              const float* __restrict__ bfc,
                                              const float* __restrict__ Wp,
                                              float* __restrict__ pts0,
                                              float* __restrict__ pts1,
                                              float* __restrict__ spd,
                                              float* __restrict__ mlp_p,
                                              float* __restrict__ E,
                                              float* __restrict__ cE,
                                              float* __restrict__ deg,
                                              float* __restrict__ bmaxp,
                                              float* __restrict__ out) {
    __shared__ __align__(16) S1 sm;
    int blk = blockIdx.x, tid = threadIdx.x, lane = tid & 63, w = tid >> 6;
    if (blk < 256) {
        // ---- A-pass ----
        int b = blk >> 3, jg = blk & 7;
        const float4* xr = (const float4*)(x + b * (NN * FF));
        float4* s4 = (float4*)sm.a.xb;
        for (int i = tid; i < 1792; i += 1024) s4[i] = xr[i];
        __syncthreads();
        sm.a.l0[tid] = sm.a.xb[tid * FF + 1];
        sm.a.l1[tid] = sm.a.xb[tid * FF + 2];
        __syncthreads();
        int jA = jg * 128 + lane, jB = jA + 64;
        float pj0a = sm.a.l0[jA], pj1a = sm.a.l1[jA];
        float pj0b = sm.a.l0[jB], pj1b = sm.a.l1[jB];
        const float4* v0p = (const float4*)&sm.a.l0[w * 64];
        const float4* v1p = (const float4*)&sm.a.l1[w * 64];
        unsigned dA = 0u, dB = 0u;
        float mx = 0.f;
#pragma unroll 4
        for (int g = 0; g < 16; ++g) {
            float4 v0 = v0p[g], v1 = v1p[g];
            float dx, dy, d2a, d2b;
            dx = pj0a - v0.x; dy = pj1a - v1.x; d2a = fmaf(dy, dy, dx * dx);
            dx = pj0b - v0.x; dy = pj1b - v1.x; d2b = fmaf(dy, dy, dx * dx);
            dA += (d2a <= 0.09f); dB += (d2b <= 0.09f);
            mx = fmaxf(mx, fmaxf(d2a, d2b));
            dx = pj0a - v0.y; dy = pj1a - v1.y; d2a = fmaf(dy, dy, dx * dx);
            dx = pj0b - v0.y; dy = pj1b - v1.y; d2b = fmaf(dy, dy, dx * dx);
            dA += (d2a <= 0.09f); dB += (d2b <= 0.09f);
            mx = fmaxf(mx, fmaxf(d2a, d2b));
            dx = pj0a - v0.z; dy = pj1a - v1.z; d2a = fmaf(dy, dy, dx * dx);
            dx = pj0b - v0.z; dy = pj1b - v1.z; d2b = fmaf(dy, dy, dx * dx);
            dA += (d2a <= 0.09f); dB += (d2b <= 0.09f);
            mx = fmaxf(mx, fmaxf(d2a, d2b));
            dx = pj0a - v0.w; dy = pj1a - v1.w; d2a = fmaf(dy, dy, dx * dx);
            dx = pj0b - v0.w; dy = pj1b - v1.w; d2b = fmaf(dy, dy, dx * dx);
            dA += (d2a <= 0.09f); dB += (d2b <= 0.09f);
            mx = fmaxf(mx, fmaxf(d2a, d2b));
        }
        sm.a.s2[tid] = (float)dA;
        sm.a.s3[tid] = (float)dB;
        mx = wave_max(mx);
        if (lane == 0) sm.a.wred[w] = mx;
        __syncthreads();
        if (tid < 64) {
            float s = 0.f;
#pragma unroll
            for (int kk = 0; kk < 16; ++kk) s += sm.a.s2[kk * 64 + tid];
            deg[b * NN + jg * 128 + tid] = s;
        } else if (tid < 128) {
            int t = tid - 64;
            float s = 0.f;
#pragma unroll
            for (int kk = 0; kk < 16; ++kk) s += sm.a.s3[kk * 64 + t];
            deg[b * NN + jg * 128 + 64 + t] = s;
        }
        if (tid == 0) {
            float m = sm.a.wred[0];
#pragma unroll
            for (int i = 1; i < 16; ++i) m = fmaxf(m, sm.a.wred[i]);
            bmaxp[b * 8 + jg] = m;
        }
    } else if (blk < 288) {
        // ---- repack + speed + out zero-init (K2 atomically accumulates) ----
        int b = blk - 256;
        const float4* xr = (const float4*)(x + b * (NN * FF));
        float4* s4 = (float4*)sm.p.xb;
        for (int i = tid; i < 1792; i += 1024) s4[i] = xr[i];
        if (tid < OUTN) out[b * OUTN + tid] = 0.f;
        __syncthreads();
        pts0[b * NN + tid] = sm.p.xb[tid * FF + 1];
        pts1[b * NN + tid] = sm.p.xb[tid * FF + 2];
        float vx = sm.p.xb[tid * FF + 3], vy = sm.p.xb[tid * FF + 4];
        float sp = sqrtf(fmaf(vx, vx, vy * vy));
        sp = wave_sum(sp);
        if (lane == 0) sm.p.wred[w] = sp;
        __syncthreads();
        if (tid == 0) {
            float s = 0.f;
#pragma unroll
            for (int i = 0; i < 16; ++i) s += sm.p.wred[i];
            spd[b] = s;
        }
    } else if (blk < 296) {
        // ---- weight collapse ----
        int o = blk - 288;
        if (tid < HID) sm.c.l0[tid] = Wp[o * CATN + MLPH + tid];
        __syncthreads();
        if (tid < HID) {
            float a = 0.f;
#pragma unroll 8
            for (int m = 0; m < HID; ++m) a = fmaf(sm.c.l0[m], Wfc[m * HID + tid], a);
            sm.c.l1[tid] = a;
            sm.c.r2[tid] = sm.c.l0[tid] * bfc[tid];
        }
        __syncthreads();
        if (tid < HID) {
            float e = 0.f;
#pragma unroll 8
            for (int k = 0; k < HID; ++k) e = fmaf(sm.c.l1[k], W2[k * HID + tid], e);
            E[o * HID + tid] = e;
            float c = fmaf(sm.c.l1[tid], b2[tid], sm.c.r2[tid]);
            c = wave_sum(c);
            if (lane == 0) sm.c.wred[w] = c;
        }
        __syncthreads();
        if (tid == 0) cE[o] = sm.c.wred[0] + sm.c.wred[1] + sm.c.wred[2] + sm.c.wred[3];
    } else {
        // ---- MLP-L1 GEMV: 2 blocks per h, 16 batches (1 per wave) each ----
        int t = blk - 296, h = t >> 1, half = t & 1;
        const float4* wr = (const float4*)(Wm0 + h * (NN * FF));
        float4* s4 = (float4*)sm.m.wb;
        for (int i = tid; i < 1792; i += 1024) s4[i] = wr[i];
        __syncthreads();
        int b = half * 16 + w;
        const float4* xr = (const float4*)(x + b * (NN * FF));
        float4 a4 = {0.f, 0.f, 0.f, 0.f};
#pragma unroll 7
        for (int it = 0; it < 28; ++it) {
            float4 xv = xr[it * 64 + lane];
            float4 wv = s4[it * 64 + lane];
            a4.x = fmaf(wv.x, xv.x, a4.x);
            a4.y = fmaf(wv.y, xv.y, a4.y);
            a4.z = fmaf(wv.z, xv.z, a4.z);
            a4.w = fmaf(wv.w, xv.w, a4.w);
        }
        float s = (a4.x + a4.y) + (a4.z + a4.w);
        s = wave_sum(s);
        if (lane == 0) mlp_p[b * MLPH + h] = s;
    }
}

// K2: B-pass per (b,jg) with FUSED h/hsum partial, then each block projects
// its OWN 256-float hs-partial through E down to 8 floats and atomicAdd's
// them into out[b][:]. hs enters out linearly, so Σ_jg E@hpart_jg == E@hs —
// no inter-block ordering, no fences, no extra kernel. Global atomics are
// device-scope coherent by default on CDNA. Block jg==0 folds in the MLP
// branch, global branch, cE and bp (all block-local data from K1).
struct S2 {
    float l0[NN], l1[NN], di[NN];
    float r0a[NN], r1a[NN], r2a[NN], r0b[NN], r1b[NN], r2b[NN];
    float q0[128], q1[128], qw[128];
    // reused regions (dead after their producing phase):
    //   hsl  = l0[0..256)    (l0 dead after pass-1 compute)
    //   sx1  = l1[0..64)     (l1 dead after pass-1 compute)
    //   sxf2 = l1[64..128)
    //   sglo = l1[128..136)
};

__global__ __launch_bounds__(1024, 4) void k2(const float* __restrict__ pts0,
                                              const float* __restrict__ pts1,
                                              const float* __restrict__ deg,
                                              const float* __restrict__ W1,
                                              const float* __restrict__ b1,
                                              const float* __restrict__ Wg,
                                              const float* __restrict__ bg,
                                              const float* __restrict__ Wm1,
                                              const float* __restrict__ bm1,
                                              const float* __restrict__ Wp,
                                              const float* __restrict__ bp,
                                              const float* __restrict__ bm0,
                                              const float* __restrict__ mlp_p,
                                              const float* __restrict__ bmaxp,
                                              const float* __restrict__ spd,
                                              const float* __restrict__ E,
                                              const float* __restrict__ cE,
                                              float* __restrict__ out) {
    __shared__ __align__(16) S2 sm;
    int blk = blockIdx.x, tid = threadIdx.x, lane = tid & 63, w = tid >> 6;
    int b = blk >> 3, jg = blk & 7;
    float* hsl  = sm.l0;        // aliases, see struct comment
    float* sx1  = sm.l1;
    float* sxf2 = sm.l1 + 64;
    float* sglo = sm.l1 + 128;
    sm.l0[tid] = pts0[b * NN + tid];
    sm.l1[tid] = pts1[b * NN + tid];
    sm.di[tid] = 1.0f / sqrtf(deg[b * NN + tid]);
    __syncthreads();
    int jA = jg * 128 + lane, jB = jA + 64;
    float pj0a = sm.l0[jA], pj1a = sm.l1[jA];
    float pj0b = sm.l0[jB], pj1b = sm.l1[jB];
    const float4* v0p = (const float4*)&sm.l0[w * 64];
    const float4* v1p = (const float4*)&sm.l1[w * 64];
    const float4* vdp = (const float4*)&sm.di[w * 64];
    float a0a = 0.f, a1a = 0.f, asa = 0.f;
    float a0b = 0.f, a1b = 0.f, asb = 0.f;
#pragma unroll 4
    for (int g = 0; g < 16; ++g) {
        float4 v0 = v0p[g], v1 = v1p[g], vd = vdp[g];
        float dx, dy, d2, t;
        dx = pj0a - v0.x; dy = pj1a - v1.x; d2 = fmaf(dy, dy, dx * dx);
        t = (d2 <= 0.09f) ? vd.x : 0.0f;
        a0a = fmaf(t, v0.x, a0a); a1a = fmaf(t, v1.x, a1a); asa += t;
        dx = pj0b - v0.x; dy = pj1b - v1.x; d2 = fmaf(dy, dy, dx * dx);
        t = (d2 <= 0.09f) ? vd.x : 0.0f;
        a0b = fmaf(t, v0.x, a0b); a1b = fmaf(t, v1.x, a1b); asb += t;
        dx = pj0a - v0.y; dy = pj1a - v1.y; d2 = fmaf(dy, dy, dx * dx);
        t = (d2 <= 0.09f) ? vd.y : 0.0f;
        a0a = fmaf(t, v0.y, a0a); a1a = fmaf(t, v1.y, a1a); asa += t;
        dx = pj0b - v0.y; dy = pj1b - v1.y; d2 = fmaf(dy, dy, dx * dx);
        t = (d2 <= 0.09f) ? vd.y : 0.0f;
        a0b = fmaf(t, v0.y, a0b); a1b = fmaf(t, v1.y, a1b); asb += t;
        dx = pj0a - v0.z; dy = pj1a - v1.z; d2 = fmaf(dy, dy, dx * dx);
        t = (d2 <= 0.09f) ? vd.z : 0.0f;
        a0a = fmaf(t, v0.z, a0a); a1a = fmaf(t, v1.z, a1a); asa += t;
        dx = pj0b - v0.z; dy = pj1b - v1.z; d2 = fmaf(dy, dy, dx * dx);
        t = (d2 <= 0.09f) ? vd.z : 0.0f;
        a0b = fmaf(t, v0.z, a0b); a1b = fmaf(t, v1.z, a1b); asb += t;
        dx = pj0a - v0.w; dy = pj1a - v1.w; d2 = fmaf(dy, dy, dx * dx);
        t = (d2 <= 0.09f) ? vd.w : 0.0f;
        a0a = fmaf(t, v0.w, a0a); a1a = fmaf(t, v1.w, a1a); asa += t;
        dx = pj0b - v0.w; dy = pj1b - v1.w; d2 = fmaf(dy, dy, dx * dx);
        t = (d2 <= 0.09f) ? vd.w : 0.0f;
        a0b = fmaf(t, v0.w, a0b); a1b = fmaf(t, v1.w, a1b); asb += t;
    }
    sm.r0a[tid] = a0a; sm.r1a[tid] = a1a; sm.r2a[tid] = asa;
    sm.r0b[tid] = a0b; sm.r1b[tid] = a1b; sm.r2b[tid] = asb;
    __syncthreads();
    if (tid < 128) {
        int t = tid & 63;
        const float* R0 = (tid < 64) ? sm.r0a : sm.r0b;
        const float* R1 = (tid < 64) ? sm.r1a : sm.r1b;
        const float* R2 = (tid < 64) ? sm.r2a : sm.r2b;
        int j = jg * 128 + tid;     // local index == tid for tid<128
        float s0 = 0.f, s1 = 0.f, ss = 0.f;
#pragma unroll
        for (int kk = 0; kk < 16; ++kk) {
            s0 += R0[kk * 64 + t];
            s1 += R1[kk * 64 + t];
            ss += R2[kk * 64 + t];
        }
        float dj = sm.di[j];
        sm.q0[tid] = dj * s0;
        sm.q1[tid] = dj * s1;
        sm.qw[tid] = dj * ss * (1.0f / NN);
    } else if (jg == 0 && tid < 192) {
        int t2 = tid - 128;         // xf1 = relu(mlp row dot + bm0)
        sx1[t2] = fmaxf(mlp_p[b * MLPH + t2] + bm0[t2], 0.f);
    }
    __syncthreads();
    // ---- fused h + weighted hsum partial over this block's 128 j ----
    {
        int h = tid & 255, jq = tid >> 8;
        float w10 = W1[2 * h], w11 = W1[2 * h + 1], bb = b1[h];
        const float4* q0v = (const float4*)&sm.q0[jq * 32];
        const float4* q1v = (const float4*)&sm.q1[jq * 32];
        const float4* qwv = (const float4*)&sm.qw[jq * 32];
        float acc = 0.f;
#pragma unroll
        for (int g = 0; g < 8; ++g) {
            float4 qa = q0v[g], qb = q1v[g], qw4 = qwv[g];
            acc = fmaf(qw4.x, fmaxf(fmaf(qb.x, w11, fmaf(qa.x, w10, bb)), 0.f), acc);
            acc = fmaf(qw4.y, fmaxf(fmaf(qb.y, w11, fmaf(qa.y, w10, bb)), 0.f), acc);
            acc = fmaf(qw4.z, fmaxf(fmaf(qb.z, w11, fmaf(qa.z, w10, bb)), 0.f), acc);
            acc = fmaf(qw4.w, fmaxf(fmaf(qb.w, w11, fmaf(qa.w, w10, bb)), 0.f), acc);
        }
        sm.r0a[jq * 256 + h] = acc;   // r-arrays dead after the sync above
    }
    __syncthreads();
    if (tid < HID) {
        hsl[tid] = sm.r0a[tid] + sm.r0a[256 + tid] + sm.r0a[512 + tid] + sm.r0a[768 + tid];
    } else if (jg == 0 && tid < HID + MLPH) {
        int t2 = tid - HID;
        float a = bm1[t2];
        const float* wv = Wm1 + t2 * MLPH;
#pragma unroll
        for (int k = 0; k < MLPH; ++k) a = fmaf(wv[k], sx1[k], a);
        sxf2[t2] = fmaxf(a, 0.f);
    } else if (jg == 0 && tid < HID + MLPH + 8) {
        int t2 = tid - HID - MLPH;
        float mx = 0.f;
#pragma unroll
        for (int g = 0; g < 8; ++g) mx = fmaxf(mx, bmaxp[b * 8 + g]);
        float avg  = spd[b] * (1.0f / NN);
        float dens = 1.0f / sqrtf(mx);
        sglo[t2] = fmaxf(fmaf(Wg[t2 * 2], avg, fmaf(Wg[t2 * 2 + 1], dens, bg[t2])), 0.f);
    }
    __syncthreads();
    // ---- project partial hs through E -> 8 floats, atomic fan-in to out ----
    if (tid < 512) {
        int o = tid >> 6, ln = tid & 63;
        const float* Eo = E + o * HID;
        float a = Eo[ln] * hsl[ln];
        a = fmaf(Eo[ln + 64],  hsl[ln + 64],  a);
        a = fmaf(Eo[ln + 128], hsl[ln + 128], a);
        a = fmaf(Eo[ln + 192], hsl[ln + 192], a);
        if (jg == 0) a = fmaf(Wp[o * CATN + ln], sxf2[ln], a);
        a = wave_sum(a);
        if (ln == 0) {
            if (jg == 0) {
                const float* wg = Wp + o * CATN + MLPH + HID;
#pragma unroll
                for (int g = 0; g < 8; ++g) a = fmaf(wg[g], sglo[g], a);
                a += cE[o] + bp[o];
            }
            atomicAdd(&out[b * OUTN + o], a);
        }
    }
}

extern "C" void kernel_launch(void* const* d_in, const int* in_sizes, int n_in,
                              void* d_out, int out_size, void* d_ws, size_t ws_size,
                              hipStream_t stream) {
    const float* x   = (const float*)d_in[0];
    const float* W1  = (const float*)d_in[1];
    const float* b1  = (const float*)d_in[2];
    const float* W2  = (const float*)d_in[3];
    const float* b2  = (const float*)d_in[4];
    const float* Wfc = (const float*)d_in[5];
    const float* bfc = (const float*)d_in[6];
    const float* Wg  = (const float*)d_in[7];
    const float* bg  = (const float*)d_in[8];
    const float* Wm0 = (const float*)d_in[9];
    const float* bm0 = (const float*)d_in[10];
    const float* Wm1 = (const float*)d_in[11];
    const float* bm1 = (const float*)d_in[12];
    const float* Wp  = (const float*)d_in[13];
    const float* bp  = (const float*)d_in[14];
    float* out = (float*)d_out;
    float* ws  = (float*)d_ws;

    float* pts0  = ws;              // 32768
    float* pts1  = ws + 32768;      // 32768
    float* deg   = ws + 65536;      // 32768
    float* mlp_p = ws + 98304;      // 2048
    float* bmaxp = ws + 100352;     // 256
    float* spd   = ws + 100608;     // 32
    float* E     = ws + 100640;     // 2048
    float* cE    = ws + 102688;     // 8
    // every ws cell is written before it is read each iteration -> no zero-init.

    k1<<<424, 1024, 0, stream>>>(x, Wm0, W2, b2, Wfc, bfc, Wp,
                                 pts0, pts1, spd, mlp_p, E, cE, deg, bmaxp, out);
    k2<<<256, 1024, 0, stream>>>(pts0, pts1, deg, W1, b1, Wg, bg, Wm1, bm1,
                                 Wp, bp, bm0, mlp_p, bmaxp, spd, E, cE, out);
}